// Round 8
// baseline (460.924 us; speedup 1.0000x reference)
//
#include <hip/hip_runtime.h>
#include <cstdint>

typedef __bf16 bf16x8 __attribute__((ext_vector_type(8)));
typedef float f32x4 __attribute__((ext_vector_type(4)));
typedef unsigned short u16x8 __attribute__((ext_vector_type(8)));

#define NH 16
#define HD 128
#define SEQ 2048
#define DIM 2048
#define QKVO 6144   /* 48*128 */

__device__ __forceinline__ unsigned short f32_bf16(float f) {
  uint32_t u = __builtin_bit_cast(uint32_t, f);
  u += 0x7fffu + ((u >> 16) & 1u);
  return (unsigned short)(u >> 16);
}

// pack two f32 -> two bf16 in one u32 (lo = a, hi = b), RNE
__device__ __forceinline__ uint32_t cvt_pk_bf16(float a, float b) {
  uint32_t r;
  asm("v_cvt_pk_bf16_f32 %0, %1, %2" : "=v"(r) : "v"(a), "v"(b));
  return r;
}

// async global->LDS, 16B/lane. lds dst must be wave-uniform base (+lane*16B).
__device__ __forceinline__ void gl2lds16(const void* g, void* l) {
  __builtin_amdgcn_global_load_lds(
      (const __attribute__((address_space(1))) uint32_t*)g,
      (__attribute__((address_space(3))) uint32_t*)l,
      16, 0, 0);
}

// ---------------- elementwise f32 -> bf16 (8 elems/thread) -----------------
__global__ __launch_bounds__(256) void cvt_f32_bf16(
    const float* __restrict__ in, unsigned short* __restrict__ out) {
  long i = ((long)blockIdx.x * 256 + threadIdx.x) * 8;
  f32x4 a = *(const f32x4*)(in + i);
  f32x4 b = *(const f32x4*)(in + i + 4);
  u16x8 r;
#pragma unroll
  for (int j = 0; j < 4; j++) { r[j] = f32_bf16(a[j]); r[4 + j] = f32_bf16(b[j]); }
  *(u16x8*)(out + i) = r;
}

// ------- 64x64 tiled transpose + f32->bf16: out[C][R] = bf16(in[R][C])^T ---
__global__ __launch_bounds__(256) void transpose_f32_bf16(
    const float* __restrict__ in, unsigned short* __restrict__ out,
    int R, int C) {
  __shared__ unsigned short tile[64][65];
  const int t = threadIdx.x, tx = t & 63, ty = t >> 6;
  const long r0 = (long)blockIdx.y * 64, c0 = (long)blockIdx.x * 64;
  for (int i = 0; i < 16; i++) {
    int row = ty + i * 4;
    tile[row][tx] = f32_bf16(in[(r0 + row) * C + c0 + tx]);
  }
  __syncthreads();
  for (int i = 0; i < 16; i++) {
    int row = ty + i * 4;
    out[(c0 + row) * R + r0 + tx] = tile[tx][row];
  }
}

// ------------- extract V head-slices from qkv, transpose to VT[bh][d][t] ---
__global__ __launch_bounds__(256) void transpose_v(
    const unsigned short* __restrict__ qkv, unsigned short* __restrict__ vT) {
  // grid: x = SEQ/64, y = HD/64 (=2), z = B*NH
  __shared__ unsigned short tile[64][65];
  const int t = threadIdx.x, tx = t & 63, ty = t >> 6;
  const int bh = blockIdx.z, b = bh >> 4, h = bh & 15;
  const long t0 = (long)blockIdx.x * 64;
  const int d0 = blockIdx.y * 64;
  const unsigned short* src = qkv + (long)b * SEQ * QKVO + 2 * NH * HD + h * HD;
  for (int i = 0; i < 16; i++) {
    int row = ty + i * 4;
    tile[row][tx] = src[(t0 + row) * QKVO + d0 + tx];
  }
  __syncthreads();
  unsigned short* dst = vT + ((long)bh * HD + d0) * SEQ + t0;
  for (int i = 0; i < 16; i++) {
    int row = ty + i * 4;
    dst[(long)row * SEQ + tx] = tile[tx][row];
  }
}

// ---- C[:,ldc] = A[:,lda] @ BT[:,ldb]^T  (bf16 in, fp32 accum, OutT out) ---
// m97 structure: used for GEMM2 (N=2048 -> 512 blocks at 128x128; beats a
// 128-block 256² launch by ~11 us — round-7 measurement).
template <typename OutT>
__global__ __launch_bounds__(256) void gemm_bt(
    const unsigned short* __restrict__ A, int lda,
    const unsigned short* __restrict__ BT, int ldb,
    OutT* __restrict__ C, int ldc, int K) {
  __shared__ __align__(16) unsigned short As[128 * 32];
  __shared__ __align__(16) unsigned short Bs[128 * 32];
  const int t = threadIdx.x;
  const int lane = t & 63, w = t >> 6;
  const int quad = lane >> 4, l16 = lane & 15;
  const int wm = (w & 1) * 64, wn = (w >> 1) * 64;
  const long m0 = (long)blockIdx.y * 128, n0 = (long)blockIdx.x * 128;

  f32x4 acc[4][4] = {};
  const int rowA = t >> 2, kslot = (t & 3) * 8;
  const unsigned short* Ag = A + (m0 + rowA) * (long)lda + kslot;
  const unsigned short* Bg = BT + (n0 + rowA) * (long)ldb + kslot;
  unsigned short* AsBase = &As[w * 512];
  unsigned short* BsBase = &Bs[w * 512];

  for (int k0 = 0; k0 < K; k0 += 32) {
    __syncthreads();  // prev iteration's LDS readers done
    gl2lds16(Ag + k0, AsBase);
    gl2lds16(Ag + 64 * (long)lda + k0, AsBase + 2048);
    gl2lds16(Bg + k0, BsBase);
    gl2lds16(Bg + 64 * (long)ldb + k0, BsBase + 2048);
    __syncthreads();  // drains vmcnt: staged tile visible

    bf16x8 af[4], bf[4];
#pragma unroll
    for (int mt = 0; mt < 4; mt++)
      af[mt] = *(const bf16x8*)&As[(wm + mt * 16 + l16) * 32 + quad * 8];
#pragma unroll
    for (int nt = 0; nt < 4; nt++)
      bf[nt] = *(const bf16x8*)&Bs[(wn + nt * 16 + l16) * 32 + quad * 8];
#pragma unroll
    for (int mt = 0; mt < 4; mt++)
#pragma unroll
      for (int nt = 0; nt < 4; nt++)
        acc[mt][nt] = __builtin_amdgcn_mfma_f32_16x16x32_bf16(
            af[mt], bf[nt], acc[mt][nt], 0, 0, 0);
  }

#pragma unroll
  for (int mt = 0; mt < 4; mt++) {
    long row = m0 + wm + mt * 16 + quad * 4;
#pragma unroll
    for (int r = 0; r < 4; r++) {
      OutT* crow = C + (row + r) * (long)ldc + n0 + wn + l16;
#pragma unroll
      for (int nt = 0; nt < 4; nt++) {
        float v = acc[mt][nt][r];
        if constexpr (sizeof(OutT) == 2) crow[nt * 16] = f32_bf16(v);
        else                             crow[nt * 16] = v;
      }
    }
  }
}

// ============ 256x256 GEMM, 1-barrier/K-tile, 3-deep circular LDS ===========
// Round-8 structure. R2/R6/R7 all plateaued at ~131 us because the per-phase
// double-barrier SERIALIZED LDS reads against MFMA (reads ~2300cy + MFMA
// ~2480cy per K-tile = measured ~4900cy). The read->MFMA dep is PER-WAVE, so
// only stage->read (RAW) and read->stage (WAR) need block sync:
//   per K-tile: stage(buf[T+2]) ; 12 ds_read + 32 MFMA from buf[T]
//               (compiler-interleaved, NO fences) ; vmcnt(4) ; s_barrier.
// BK=32, 3 buffers x (A 16KB + B 16KB) = 96KB LDS.
// RAW: tile T staged at top of T-2; drained by vmcnt(4) at end of T-1 (all
//      but T-1's own 4 stages), then barrier -> visible to all waves at T.
// WAR: buffer written at top of T was read at T-1; waves reach T-1's barrier
//      only after issuing all MFMAs ==> their ds_reads have returned.
// Counted waits are stage-group aligned: each fence-delimited region holds
// exactly 4 gl2lds (prologue uses order-insensitive vmcnt(0) — R3 lesson).
// LDS swizzle for 64B rows: granule g at row r stored at g^((r>>1)&3); wave
// read pattern covers banks exactly (verified by hand) -> conflict-free.
// NO XCD swizzle (R5: row-chunking doubled FETCH; default col-slices win).
template <typename OutT>
__global__ __launch_bounds__(512, 2) void gemm256_bt(
    const unsigned short* __restrict__ A, int lda,
    const unsigned short* __restrict__ BT, int ldb,
    OutT* __restrict__ C, int ldc, int K) {
  __shared__ __align__(16) unsigned short As[3][8192];
  __shared__ __align__(16) unsigned short Bs[3][8192];
  const int t = threadIdx.x, lane = t & 63, w = t >> 6;
  const int l16 = lane & 15, quad = lane >> 4;
  const int wn = w & 3, wm = w >> 2;
  const int NT = K >> 5;                       // BK = 32
  const long m0 = (long)blockIdx.y * 256, n0 = (long)blockIdx.x * 256;

  // staging: 512 thr x 16B = 8KB = 128 rows/sweep; 2 sweeps per operand.
  // thread -> row (t>>2), phys granule (t&3); logical = phys ^ ((row>>1)&3).
  // (row+128)>>1 & 3 == (row>>1)&3, so one swizzled pointer serves both sweeps.
  const int srow = t >> 2;
  const int sgr = (t & 3) ^ ((srow >> 1) & 3);
  const unsigned short* Ag = A + (m0 + srow) * (long)lda + sgr * 8;
  const unsigned short* Bg = BT + (n0 + srow) * (long)ldb + sgr * 8;

  // read side: frag rows are (16-mult + l16) so (row>>1)&3 == (l16>>1)&3
  const int pg = quad ^ ((l16 >> 1) & 3);
  const int aBase = (wm * 128 + l16) * 32 + pg * 8;
  const int bBase = (wn * 64 + l16) * 32 + pg * 8;

  f32x4 acc[8][4] = {};

  auto stage = [&](int buf, long k0) {
    gl2lds16(Ag + k0, &As[buf][w * 512]);
    gl2lds16(Ag + 128 * (long)lda + k0, &As[buf][4096 + w * 512]);
    gl2lds16(Bg + k0, &Bs[buf][w * 512]);
    gl2lds16(Bg + 128 * (long)ldb + k0, &Bs[buf][4096 + w * 512]);
  };

#define GBAR asm volatile("s_barrier" ::: "memory")

  // prologue: tiles 0,1 -> bufs 0,1; order-insensitive full drain.
  stage(0, 0);
  if (NT > 1) stage(1, 32);
  asm volatile("s_waitcnt vmcnt(0)" ::: "memory");
  GBAR;

  int c = 0;
  for (int T = 0; T < NT; ++T) {
    const bool s2 = (T + 2 < NT), s1 = (T + 1 < NT);
    const int s = (c == 0) ? 2 : c - 1;        // buffer for tile T+2
    if (s2) stage(s, ((long)T + 2) << 5);

    // 12 ds_read_b128 + 32 MFMA, no fences: compiler interleaves, other
    // waves drift -> LDS reads overlap MFMA instead of serializing.
    bf16x8 bf[4], af[8];
#pragma unroll
    for (int nf = 0; nf < 4; ++nf)
      bf[nf] = *(const bf16x8*)&Bs[c][bBase + nf * 512];
#pragma unroll
    for (int mf = 0; mf < 8; ++mf)
      af[mf] = *(const bf16x8*)&As[c][aBase + mf * 512];
#pragma unroll
    for (int mf = 0; mf < 8; ++mf)
#pragma unroll
      for (int nf = 0; nf < 4; ++nf)
        acc[mf][nf] = __builtin_amdgcn_mfma_f32_16x16x32_bf16(
            af[mf], bf[nf], acc[mf][nf], 0, 0, 0);

    if (s2)      asm volatile("s_waitcnt vmcnt(4)" ::: "memory");
    else if (s1) asm volatile("s_waitcnt vmcnt(0)" ::: "memory");
    GBAR;
    c = (c == 2) ? 0 : c + 1;
  }

  // epilogue: C row = m0+wm*128+mf*16+quad*4+r, col = n0+wn*64+nf*16+l16
#pragma unroll
  for (int mf = 0; mf < 8; ++mf) {
    const long row = m0 + wm * 128 + mf * 16 + quad * 4;
#pragma unroll
    for (int r = 0; r < 4; ++r) {
      OutT* crow = C + (row + r) * (long)ldc + n0 + wn * 64 + l16;
#pragma unroll
      for (int nf = 0; nf < 4; ++nf) {
        float v = acc[mf][nf][r];
        if constexpr (sizeof(OutT) == 2) crow[nf * 16] = f32_bf16(v);
        else                             crow[nf * 16] = v;
      }
    }
  }
#undef GBAR
}

// -------- flash attention: 128 q/block, 32 q/wave (mt=2), 64-key chunks ----
// Swapped QK^T (S^T = mfma(K,Q)): lane owns one query column -> in-lane
// softmax, P packed via cvt_pk and stored as ds_write_b64 (no scalar writes).
// Defer-max (THR=8 exp2-units) skips the O-rescale when max doesn't grow.
// Software-pipelined K/V prefetch into regs; P roundtrip per-wave (no barrier).
// Writes O in place over the Q columns of qkv.
#define KSTR 136  /* 64 x 136 padded K tile  */
#define VSTR 72   /* 128 x 72 padded VT tile */
__global__ __launch_bounds__(256, 2) void attn_kernel(
    unsigned short* qkv, const unsigned short* __restrict__ vT) {
  __shared__ __align__(16) unsigned short Ks[64 * KSTR];
  __shared__ __align__(16) unsigned short Vs[128 * VSTR];
  __shared__ __align__(16) unsigned short Ps[4][32 * VSTR];

  const int t = threadIdx.x, lane = t & 63, w = t >> 6;
  const int quad = lane >> 4, l16 = lane & 15;
  const int q0 = blockIdx.x * 128, h = blockIdx.y, b = blockIdx.z;
  const long row0 = (long)b * SEQ;

  // Q fragments (2 m-tiles): B-operand row = w*32 + mt*16 + l16 (query)
  bf16x8 qf[2][4];
#pragma unroll
  for (int mt = 0; mt < 2; mt++) {
    const unsigned short* Qp =
        qkv + (row0 + q0 + w * 32 + mt * 16 + l16) * (long)QKVO + h * HD + quad * 8;
#pragma unroll
    for (int c = 0; c < 4; c++) qf[mt][c] = *(const bf16x8*)(Qp + c * 32);
  }

  // per-lane stats: lane (quad,l16) owns query mt*16+l16 (replicated over quad)
  float m_l[2], l_l[2];
  f32x4 o[2][8] = {};
  m_l[0] = m_l[1] = -1e30f;
  l_l[0] = l_l[1] = 0.f;
  const float c2 = 0.08838834764831845f * 1.4426950408889634f; // 1/sqrt(128)*log2(e)
  const float thr = 8.0f / c2;  // defer-max threshold in raw-logit domain

  const unsigned short* Kg = qkv + row0 * QKVO + NH * HD + h * HD;
  const unsigned short* Vg = vT + ((long)(b * NH + h)) * HD * SEQ;

  // prefetch chunk 0 into regs
  bf16x8 kr[4], vr[4];
#pragma unroll
  for (int i = 0; i < 4; i++) {
    int s = i * 256 + t;  // K tile: [key = s>>4][dchunk = s&15]
    kr[i] = *(const bf16x8*)(Kg + (long)(s >> 4) * QKVO + (s & 15) * 8);
  }
#pragma unroll
  for (int i = 0; i < 4; i++) {
    int s = i * 256 + t;  // VT tile: [d = s>>3][keychunk = s&7]
    vr[i] = *(const bf16x8*)(Vg + (long)(s >> 3) * SEQ + (s & 7) * 8);
  }

  for (int kc = 0; kc < SEQ; kc += 64) {
    __syncthreads();  // prev chunk's LDS readers done
#pragma unroll
    for (int i = 0; i < 4; i++) {
      int s = i * 256 + t;
      *(bf16x8*)&Ks[(s >> 4) * KSTR + (s & 15) * 8] = kr[i];
    }
#pragma unroll
    for (int i = 0; i < 4; i++) {
      int s = i * 256 + t;
      *(bf16x8*)&Vs[(s >> 3) * VSTR + (s & 7) * 8] = vr[i];
    }
    __syncthreads();  // tiles visible

    // issue next chunk's global loads now; latency hidden under compute
    if (kc + 64 < SEQ) {
#pragma unroll
      for (int i = 0; i < 4; i++) {
        int s = i * 256 + t;
        kr[i] = *(const bf16x8*)(Kg + (long)(kc + 64 + (s >> 4)) * QKVO + (s & 15) * 8);
      }
#pragma unroll
      for (int i = 0; i < 4; i++) {
        int s = i * 256 + t;
        vr[i] = *(const bf16x8*)(Vg + (long)(s >> 3) * SEQ + kc + 64 + (s & 7) * 8);
      }
    }

    // S^T = K Q^T : D row = key (kt*16+quad*4+r), D col = query (l16)
    f32x4 st[2][4];
#pragma unroll
    for (int kt = 0; kt < 4; kt++) {
      f32x4 a0 = {}, a1 = {};
#pragma unroll
      for (int c = 0; c < 4; c++) {
        bf16x8 kf = *(const bf16x8*)&Ks[(kt * 16 + l16) * KSTR + c * 32 + quad * 8];
        a0 = __builtin_amdgcn_mfma_f32_16x16x32_bf16(kf, qf[0][c], a0, 0, 0, 0);
        a1 = __builtin_amdgcn_mfma_f32_16x16x32_bf16(kf, qf[1][c], a1, 0, 0, 0);
      }
      st[0][kt] = a0; st[1][kt] = a1;
    }

    // in-lane online softmax: lane holds 16 keys of its query's row
#pragma unroll
    for (int mt = 0; mt < 2; mt++) {
      float mx0 = fmaxf(fmaxf(st[mt][0][0], st[mt][0][1]),
                        fmaxf(st[mt][0][2], st[mt][0][3]));
      float mx1 = fmaxf(fmaxf(st[mt][1][0], st[mt][1][1]),
                        fmaxf(st[mt][1][2], st[mt][1][3]));
      float mx2 = fmaxf(fmaxf(st[mt][2][0], st[mt][2][1]),
                        fmaxf(st[mt][2][2], st[mt][2][3]));
      float mx3 = fmaxf(fmaxf(st[mt][3][0], st[mt][3][1]),
                        fmaxf(st[mt][3][2], st[mt][3][3]));
      float mx = fmaxf(fmaxf(mx0, mx1), fmaxf(mx2, mx3));
      mx = fmaxf(mx, __shfl_xor(mx, 16, 64));  // combine quads
      mx = fmaxf(mx, __shfl_xor(mx, 32, 64));

      // defer-max: rescale only if some query's max grew past threshold
      if (__any(mx > m_l[mt] + thr)) {
        float mn = fmaxf(m_l[mt], mx);
        float alpha = exp2f(c2 * (m_l[mt] - mn));
        m_l[mt] = mn;
        l_l[mt] *= alpha;
        // redistribute alpha to the O rows this lane holds (queries quad*4+r)
        float a_o[4];
#pragma unroll
        for (int r = 0; r < 4; r++) a_o[r] = __shfl(alpha, (quad << 2) | r, 16);
#pragma unroll
        for (int dt = 0; dt < 8; dt++)
#pragma unroll
          for (int r = 0; r < 4; r++) o[mt][dt][r] *= a_o[r];
      }

      float cm = c2 * m_l[mt];
      float sum = 0.f;
      uint32_t pk0[4], pk1[4];
#pragma unroll
      for (int kt = 0; kt < 4; kt++) {
        float p0 = exp2f(fmaf(st[mt][kt][0], c2, -cm));
        float p1 = exp2f(fmaf(st[mt][kt][1], c2, -cm));
        float p2 = exp2f(fmaf(st[mt][kt][2], c2, -cm));
        float p3 = exp2f(fmaf(st[mt][kt][3], c2, -cm));
        sum += (p0 + p1) + (p2 + p3);
        pk0[kt] = cvt_pk_bf16(p0, p1);
        pk1[kt] = cvt_pk_bf16(p2, p3);
      }
      sum += __shfl_xor(sum, 16, 64);
      sum += __shfl_xor(sum, 32, 64);
      l_l[mt] += sum;

      // P store: lane writes 4 consecutive keys for query l16 -> one b64 each
#pragma unroll
      for (int kt = 0; kt < 4; kt++) {
        uint2 w2; w2.x = pk0[kt]; w2.y = pk1[kt];
        *(uint2*)&Ps[w][(mt * 16 + l16) * VSTR + kt * 16 + quad * 4] = w2;
      }
    }
    asm volatile("s_waitcnt lgkmcnt(0)" ::: "memory");

    // O += P V : V-frag shared across both m-tiles
#pragma unroll
    for (int cc = 0; cc < 2; cc++) {
      bf16x8 pf0 = *(const bf16x8*)&Ps[w][(l16) * VSTR + cc * 32 + quad * 8];
      bf16x8 pf1 = *(const bf16x8*)&Ps[w][(16 + l16) * VSTR + cc * 32 + quad * 8];
#pragma unroll
      for (int dt = 0; dt < 8; dt++) {
        bf16x8 vf = *(const bf16x8*)&Vs[(dt * 16 + l16) * VSTR + cc * 32 + quad * 8];
        o[0][dt] = __builtin_amdgcn_mfma_f32_16x16x32_bf16(pf0, vf, o[0][dt], 0, 0, 0);
        o[1][dt] = __builtin_amdgcn_mfma_f32_16x16x32_bf16(pf1, vf, o[1][dt], 0, 0, 0);
      }
    }
  }

  // epilogue: redistribute 1/l to O rows, write O over the Q columns of qkv
  float inv_o[2][4];
#pragma unroll
  for (int mt = 0; mt < 2; mt++) {
    float linv = 1.f / l_l[mt];
#pragma unroll
    for (int r = 0; r < 4; r++) inv_o[mt][r] = __shfl(linv, (quad << 2) | r, 16);
  }
#pragma unroll
  for (int mt = 0; mt < 2; mt++) {
    long orow = row0 + q0 + w * 32 + mt * 16 + quad * 4;
    unsigned short* Op = qkv + orow * (long)QKVO + h * HD + l16;
#pragma unroll
    for (int r = 0; r < 4; r++) {
#pragma unroll
      for (int dt = 0; dt < 8; dt++)
        Op[(long)r * QKVO + dt * 16] = f32_bf16(o[mt][dt][r] * inv_o[mt][r]);
    }
  }
}

extern "C" void kernel_launch(void* const* d_in, const int* in_sizes, int n_in,
                              void* d_out, int out_size, void* d_ws, size_t ws_size,
                              hipStream_t stream) {
  const float* x     = (const float*)d_in[0];  // [4096][2048] f32
  const float* w_qkv = (const float*)d_in[1];  // [2048][6144] f32
  const float* w_out = (const float*)d_in[2];  // [2048][2048] f32
  float* out = (float*)d_out;                  // [4096][2048] f32

  // Workspace plan (peak 92,274,688 B):
  //   [0,        50331648)  qkv  bf16 [4096][6144] (Q cols later = O)
  //   [50331648, 67108864)  xbf  bf16 [4096][2048]
  //   [67108864, 92274688)  wqkvT bf16 [6144][2048]  (dead after GEMM1)
  //   [67108864, 83886080)    vT bf16 [32][128][2048] (overlays wqkvT)
  //   [83886080, 92274688)    woutT bf16 [2048][2048] (overlays wqkvT tail)
  char* ws = (char*)d_ws;
  unsigned short* qkv   = (unsigned short*)ws;
  unsigned short* xbf   = (unsigned short*)(ws + 50331648);
  unsigned short* wqkvT = (unsigned short*)(ws + 67108864);
  unsigned short* vTbuf = (unsigned short*)(ws + 67108864);
  unsigned short* woutT = (unsigned short*)(ws + 83886080);

  dim3 blk(256);
  // 1) convert x to bf16; transpose+convert w_qkv
  cvt_f32_bf16<<<4096, blk, 0, stream>>>(x, xbf);
  transpose_f32_bf16<<<dim3(QKVO / 64, DIM / 64), blk, 0, stream>>>(w_qkv, wqkvT, DIM, QKVO);
  // 2) QKV projection: qkv = xbf @ w_qkv  (bf16 out) — 1-barrier 256² kernel
  gemm256_bt<unsigned short><<<dim3(QKVO / 256, 4096 / 256), dim3(512), 0, stream>>>(
      xbf, DIM, wqkvT, DIM, qkv, QKVO, DIM);
  // 3) V transpose per (b,h) into vT (overlays dead wqkvT)
  transpose_v<<<dim3(SEQ / 64, HD / 64, 2 * NH), blk, 0, stream>>>(qkv, vTbuf);
  // 4) transpose+convert w_out (overlays wqkvT tail; after GEMM1)
  transpose_f32_bf16<<<dim3(DIM / 64, DIM / 64), blk, 0, stream>>>(w_out, woutT, DIM, DIM);
  // 5) flash attention; O written over Q columns of qkv (128 q-rows/block)
  attn_kernel<<<dim3(SEQ / 128, NH, 2), blk, 0, stream>>>(qkv, vTbuf);
  // 6) output projection: out(f32) = O @ w_out — m97 128² kernel, 512 blocks
  //    (round-7: 128-block 256² launch was ~11 us slower; reverted)
  gemm_bt<float><<<dim3(DIM / 128, 4096 / 128), blk, 0, stream>>>(
      qkv, QKVO, woutT, DIM, out, DIM, DIM);
}

// Round 9
// 412.625 us; speedup vs baseline: 1.1171x; 1.1171x over previous
//
#include <hip/hip_runtime.h>
#include <cstdint>

typedef __bf16 bf16x8 __attribute__((ext_vector_type(8)));
typedef float f32x4 __attribute__((ext_vector_type(4)));
typedef unsigned short u16x8 __attribute__((ext_vector_type(8)));

#define NH 16
#define HD 128
#define SEQ 2048
#define DIM 2048
#define QKVO 6144   /* 48*128 */

__device__ __forceinline__ unsigned short f32_bf16(float f) {
  uint32_t u = __builtin_bit_cast(uint32_t, f);
  u += 0x7fffu + ((u >> 16) & 1u);
  return (unsigned short)(u >> 16);
}

// pack two f32 -> two bf16 in one u32 (lo = a, hi = b), RNE
__device__ __forceinline__ uint32_t cvt_pk_bf16(float a, float b) {
  uint32_t r;
  asm("v_cvt_pk_bf16_f32 %0, %1, %2" : "=v"(r) : "v"(a), "v"(b));
  return r;
}

// async global->LDS, 16B/lane. lds dst must be wave-uniform base (+lane*16B).
__device__ __forceinline__ void gl2lds16(const void* g, void* l) {
  __builtin_amdgcn_global_load_lds(
      (const __attribute__((address_space(1))) uint32_t*)g,
      (__attribute__((address_space(3))) uint32_t*)l,
      16, 0, 0);
}

// ---------------- elementwise f32 -> bf16 (8 elems/thread) -----------------
__global__ __launch_bounds__(256) void cvt_f32_bf16(
    const float* __restrict__ in, unsigned short* __restrict__ out) {
  long i = ((long)blockIdx.x * 256 + threadIdx.x) * 8;
  f32x4 a = *(const f32x4*)(in + i);
  f32x4 b = *(const f32x4*)(in + i + 4);
  u16x8 r;
#pragma unroll
  for (int j = 0; j < 4; j++) { r[j] = f32_bf16(a[j]); r[4 + j] = f32_bf16(b[j]); }
  *(u16x8*)(out + i) = r;
}

// ------- 64x64 tiled transpose + f32->bf16: out[C][R] = bf16(in[R][C])^T ---
__global__ __launch_bounds__(256) void transpose_f32_bf16(
    const float* __restrict__ in, unsigned short* __restrict__ out,
    int R, int C) {
  __shared__ unsigned short tile[64][65];
  const int t = threadIdx.x, tx = t & 63, ty = t >> 6;
  const long r0 = (long)blockIdx.y * 64, c0 = (long)blockIdx.x * 64;
  for (int i = 0; i < 16; i++) {
    int row = ty + i * 4;
    tile[row][tx] = f32_bf16(in[(r0 + row) * C + c0 + tx]);
  }
  __syncthreads();
  for (int i = 0; i < 16; i++) {
    int row = ty + i * 4;
    out[(c0 + row) * R + r0 + tx] = tile[tx][row];
  }
}

// ------------- extract V head-slices from qkv, transpose to VT[bh][d][t] ---
__global__ __launch_bounds__(256) void transpose_v(
    const unsigned short* __restrict__ qkv, unsigned short* __restrict__ vT) {
  // grid: x = SEQ/64, y = HD/64 (=2), z = B*NH
  __shared__ unsigned short tile[64][65];
  const int t = threadIdx.x, tx = t & 63, ty = t >> 6;
  const int bh = blockIdx.z, b = bh >> 4, h = bh & 15;
  const long t0 = (long)blockIdx.x * 64;
  const int d0 = blockIdx.y * 64;
  const unsigned short* src = qkv + (long)b * SEQ * QKVO + 2 * NH * HD + h * HD;
  for (int i = 0; i < 16; i++) {
    int row = ty + i * 4;
    tile[row][tx] = src[(t0 + row) * QKVO + d0 + tx];
  }
  __syncthreads();
  unsigned short* dst = vT + ((long)bh * HD + d0) * SEQ + t0;
  for (int i = 0; i < 16; i++) {
    int row = ty + i * 4;
    dst[(long)row * SEQ + tx] = tile[tx][row];
  }
}

// ======================= 256x256 8-phase GEMM (GEMM1) =======================
// EXACT round-7 version (measured 131.1 us, MfmaUtil 32) — round-8's
// 1-barrier BK=32 rewrite regressed to 181 us (block-wide read-storm with no
// overlap; halved MFMA per sync). Keeping the verified 8-phase structure.
// Liveness/wait derivation: see round 5-7 notes in history.
template <typename OutT>
__global__ __launch_bounds__(512, 2) void gemm256_bt(
    const unsigned short* __restrict__ A, int lda,
    const unsigned short* __restrict__ BT, int ldb,
    OutT* __restrict__ C, int ldc, int K) {
  __shared__ __align__(16) unsigned short As[2][16384];
  __shared__ __align__(16) unsigned short Bs[2][16384];
  const int t = threadIdx.x, lane = t & 63, w = t >> 6;
  const int l16 = lane & 15, quad = lane >> 4;
  const int wn = w & 3, wm = w >> 2;
  const int NT = K >> 6;

  const long m0 = (long)blockIdx.y * 256, n0 = (long)blockIdx.x * 256;

  const int srow = (w << 3) + (lane >> 3);
  const int sgr = (lane & 7) ^ (lane >> 3);
  const unsigned short* Ag = A + (m0 + srow) * (long)lda + sgr * 8;
  const unsigned short* Bg = BT + (n0 + srow) * (long)ldb + sgr * 8;

  const int g0 = ((quad ^ (l16 & 7)) << 3);        // elements, ks=0; ks=1: ^32
  const int aBase = wm * 8192 + l16 * 64;
  const int bBase = (wn >> 1) * 8192 + (((wn & 1) << 6) + l16) * 64;

  f32x4 acc[8][4] = {};
  bf16x8 af[4][2];       // A frags for current mh
  bf16x8 bfr0[2][2];     // B nh0 frags: read at P0, live until P3
  bf16x8 bfr1[2][2];     // B nh1 frags: read at P1

  auto stageA = [&](int half, int buf, long k0) {
    const unsigned short* src = Ag + (long)half * 128 * lda + k0;
    unsigned short* dst = &As[buf][half * 8192 + (w << 3) * 64];
    gl2lds16(src, dst);
    gl2lds16(src + 64 * (long)lda, dst + 4096);
  };
  auto stageB = [&](int half, int buf, long k0) {
    const unsigned short* src = Bg + (long)half * 128 * ldb + k0;
    unsigned short* dst = &Bs[buf][half * 8192 + (w << 3) * 64];
    gl2lds16(src, dst);
    gl2lds16(src + 64 * (long)ldb, dst + 4096);
  };
  auto readA = [&](int buf, int mh) {
#pragma unroll
    for (int mf = 0; mf < 4; ++mf)
#pragma unroll
      for (int ks = 0; ks < 2; ++ks)
        af[mf][ks] = *(const bf16x8*)
            &As[buf][aBase + (mh * 64 + mf * 16) * 64 + (g0 ^ (ks << 5))];
  };
  auto readB = [&](int buf, int nh, bf16x8 (&dst)[2][2]) {
#pragma unroll
    for (int nf = 0; nf < 2; ++nf)
#pragma unroll
      for (int ks = 0; ks < 2; ++ks)
        dst[nf][ks] = *(const bf16x8*)
            &Bs[buf][bBase + (nh * 32 + nf * 16) * 64 + (g0 ^ (ks << 5))];
  };
  auto quad16 = [&](int mh, int nh, const bf16x8 (&b)[2][2]) {
#pragma unroll
    for (int mf = 0; mf < 4; ++mf)
#pragma unroll
      for (int nf = 0; nf < 2; ++nf)
#pragma unroll
        for (int ks = 0; ks < 2; ++ks)
          acc[mh * 4 + mf][nh * 2 + nf] = __builtin_amdgcn_mfma_f32_16x16x32_bf16(
              af[mf][ks], b[nf][ks], acc[mh * 4 + mf][nh * 2 + nf], 0, 0, 0);
  };

#define GBAR asm volatile("s_barrier" ::: "memory")

  // prologue: tile 0 (4 halves) -> buf0 + A0(1) -> buf1, then full drain.
  stageA(0, 0, 0); stageA(1, 0, 0); stageB(0, 0, 0); stageB(1, 0, 0);
  if (NT > 1) stageA(0, 1, 64);
  asm volatile("s_waitcnt vmcnt(0)" ::: "memory");
  GBAR;

  for (int T = 0; T < NT; ++T) {
    const int bufc = T & 1, bufn = bufc ^ 1;
    const long k1 = ((long)T + 1) << 6, k2 = ((long)T + 2) << 6;
    const bool s1 = (T + 1 < NT), s2 = (T + 2 < NT);
    // P0: reads A0 (8) + B0 (4, into bfr0, kept to P3); stage A1/B0(T+1)->bufn
    readA(bufc, 0); readB(bufc, 0, bfr0);
    if (s1) { stageA(1, bufn, k1); stageB(0, bufn, k1); }
    asm volatile("s_waitcnt lgkmcnt(8)" ::: "memory");
    GBAR;
    __builtin_amdgcn_s_setprio(1); quad16(0, 0, bfr0); __builtin_amdgcn_s_setprio(0);
    // guard B1(T) (read next phase): newer loads = A0(T+1)[2] + A1/B0(T+1)[4]
    if (s1) asm volatile("s_waitcnt vmcnt(6)" ::: "memory");
    else    asm volatile("s_waitcnt vmcnt(0)" ::: "memory");
    GBAR;
    // P1: read B1 (4); stage B1(T+1) -> bufn
    readB(bufc, 1, bfr1);
    if (s1) stageB(1, bufn, k1);
    GBAR;
    __builtin_amdgcn_s_setprio(1); quad16(0, 1, bfr1); __builtin_amdgcn_s_setprio(0);
    GBAR;
    // P2: read A1 (8); NO stage (bufc A still live here, bufn fully staged)
    readA(bufc, 1);
    GBAR;
    __builtin_amdgcn_s_setprio(1); quad16(1, 1, bfr1); __builtin_amdgcn_s_setprio(0);
    GBAR;
    // P3: no ds_reads (B0 lives in bfr0); stage A0(T+2) -> bufc (A dead @P2b)
    if (s2) stageA(0, bufc, k2);
    GBAR;
    __builtin_amdgcn_s_setprio(1); quad16(1, 0, bfr0); __builtin_amdgcn_s_setprio(0);
    // guard A0/A1/B0(T+1): newer loads = B1(T+1)[2 if s1] + A0(T+2)[2 if s2]
    if (s1 && s2) asm volatile("s_waitcnt vmcnt(4)" ::: "memory");
    else if (s1)  asm volatile("s_waitcnt vmcnt(2)" ::: "memory");
    else          asm volatile("s_waitcnt vmcnt(0)" ::: "memory");
    GBAR;
  }

  // epilogue: C rows = m0+wm*128+mh*64+mf*16+quad*4+r, cols = n0+wn*64+nh*32+nf*16+l16
#pragma unroll
  for (int mh = 0; mh < 2; ++mh)
#pragma unroll
    for (int mf = 0; mf < 4; ++mf) {
      const long row = m0 + wm * 128 + mh * 64 + mf * 16 + quad * 4;
#pragma unroll
      for (int r = 0; r < 4; ++r) {
        OutT* crow = C + (row + r) * (long)ldc + n0 + wn * 64 + l16;
#pragma unroll
        for (int nh = 0; nh < 2; ++nh)
#pragma unroll
          for (int nf = 0; nf < 2; ++nf) {
            float v = acc[mh * 4 + mf][nh * 2 + nf][r];
            if constexpr (sizeof(OutT) == 2) crow[nh * 32 + nf * 16] = f32_bf16(v);
            else                             crow[nh * 32 + nf * 16] = v;
          }
      }
    }
#undef GBAR
}

// ================= 256x128 2-phase GEMM (GEMM2, round-9) ====================
// M=4096, N=2048 -> grid 16x16 = 256 blocks = EXACTLY one round at 1/CU.
// 8 waves as 2M x 4N; per-wave out 128x32 (acc[8][2]). BK=64.
// LDS 96 KiB: As 2buf x [2 halves x 128r x 64k], Bs 2buf x [128r x 64k];
// same XOR-granule swizzle as gemm256_bt (g ^= row&7, verified conflict-free).
// SIMPLE SYNC (R3/R4/R8 lesson — only provably-safe waits): tile T+1 staged
// entirely at T-P0a into bufn (A-bufn dead since (T-1)P1b, B-bufn dead since
// (T-1)P0's MFMA consumed its reads); full ORDER-INSENSITIVE vmcnt(0) drain
// at T-P1b before the closing barrier. No counted vmcnt anywhere.
template <typename OutT>
__global__ __launch_bounds__(512, 2) void gemm256x128_bt(
    const unsigned short* __restrict__ A, int lda,
    const unsigned short* __restrict__ BT, int ldb,
    OutT* __restrict__ C, int ldc, int K) {
  __shared__ __align__(16) unsigned short As[2][16384];
  __shared__ __align__(16) unsigned short Bs[2][8192];
  const int t = threadIdx.x, lane = t & 63, w = t >> 6;
  const int l16 = lane & 15, quad = lane >> 4;
  const int wn = w & 3, wm = w >> 2;          // wm in {0,1}, wn in {0..3}
  const int NT = K >> 6;
  const long m0 = (long)blockIdx.y * 256, n0 = (long)blockIdx.x * 128;

  // staging map (identical derivation to gemm256_bt): lane covers row
  // srow (64 rows per gl2lds), phys granule (lane&7) -> logical ^(srow&7).
  const int srow = (w << 3) + (lane >> 3);
  const int sgr = (lane & 7) ^ (lane >> 3);
  const unsigned short* Ag = A + (m0 + srow) * (long)lda + sgr * 8;
  const unsigned short* Bg = BT + (n0 + srow) * (long)ldb + sgr * 8;

  // read side: frag rows are 16-mult + l16 so row&7 == l16&7
  const int g0 = ((quad ^ (l16 & 7)) << 3);
  const int aBase = wm * 8192 + l16 * 64;     // wave's A-half == wm
  const int bBase = (wn * 32 + l16) * 64;

  f32x4 acc[8][2] = {};
  bf16x8 af[4][2], bfr[2][2];

  auto stageA = [&](int buf, long k0) {       // 4 x gl2lds: 256 rows
    gl2lds16(Ag + k0, &As[buf][(w << 3) * 64]);
    gl2lds16(Ag + 64 * (long)lda + k0, &As[buf][4096 + (w << 3) * 64]);
    gl2lds16(Ag + 128 * (long)lda + k0, &As[buf][8192 + (w << 3) * 64]);
    gl2lds16(Ag + 192 * (long)lda + k0, &As[buf][12288 + (w << 3) * 64]);
  };
  auto stageB = [&](int buf, long k0) {       // 2 x gl2lds: 128 rows
    gl2lds16(Bg + k0, &Bs[buf][(w << 3) * 64]);
    gl2lds16(Bg + 64 * (long)ldb + k0, &Bs[buf][4096 + (w << 3) * 64]);
  };
  auto readA = [&](int buf, int mh) {
#pragma unroll
    for (int mf = 0; mf < 4; ++mf)
#pragma unroll
      for (int ks = 0; ks < 2; ++ks)
        af[mf][ks] = *(const bf16x8*)
            &As[buf][aBase + (mh * 64 + mf * 16) * 64 + (g0 ^ (ks << 5))];
  };
  auto readB = [&](int buf) {
#pragma unroll
    for (int nf = 0; nf < 2; ++nf)
#pragma unroll
      for (int ks = 0; ks < 2; ++ks)
        bfr[nf][ks] = *(const bf16x8*)
            &Bs[buf][bBase + nf * 1024 + (g0 ^ (ks << 5))];
  };
  auto mfmaP = [&](int mh) {
#pragma unroll
    for (int mf = 0; mf < 4; ++mf)
#pragma unroll
      for (int nf = 0; nf < 2; ++nf)
#pragma unroll
        for (int ks = 0; ks < 2; ++ks)
          acc[mh * 4 + mf][nf] = __builtin_amdgcn_mfma_f32_16x16x32_bf16(
              af[mf][ks], bfr[nf][ks], acc[mh * 4 + mf][nf], 0, 0, 0);
  };

#define GBAR asm volatile("s_barrier" ::: "memory")

  // prologue: tile 0 -> buf0, order-insensitive drain
  stageA(0, 0); stageB(0, 0);
  asm volatile("s_waitcnt vmcnt(0)" ::: "memory");
  GBAR;

  for (int T = 0; T < NT; ++T) {
    const int bufc = T & 1, bufn = bufc ^ 1;
    const bool s1 = (T + 1 < NT);
    // P0: read A0 (8) + B (4); stage tile T+1 -> bufn (6 gl2lds)
    readA(bufc, 0); readB(bufc);
    if (s1) { stageA(bufn, ((long)T + 1) << 6); stageB(bufn, ((long)T + 1) << 6); }
    asm volatile("s_waitcnt lgkmcnt(8)" ::: "memory");
    GBAR;
    __builtin_amdgcn_s_setprio(1); mfmaP(0); __builtin_amdgcn_s_setprio(0);
    GBAR;
    // P1: read A1 (8); no stage
    readA(bufc, 1);
    GBAR;
    __builtin_amdgcn_s_setprio(1); mfmaP(1); __builtin_amdgcn_s_setprio(0);
    // full drain (order-insensitive): tile T+1 completely in LDS
    if (s1) asm volatile("s_waitcnt vmcnt(0)" ::: "memory");
    GBAR;
  }

  // epilogue: row = m0+wm*128+mh*64+mf*16+quad*4+r, col = n0+wn*32+nf*16+l16
#pragma unroll
  for (int mh = 0; mh < 2; ++mh)
#pragma unroll
    for (int mf = 0; mf < 4; ++mf) {
      const long row = m0 + wm * 128 + mh * 64 + mf * 16 + quad * 4;
#pragma unroll
      for (int r = 0; r < 4; ++r) {
        OutT* crow = C + (row + r) * (long)ldc + n0 + wn * 32 + l16;
#pragma unroll
        for (int nf = 0; nf < 2; ++nf) {
          float v = acc[mh * 4 + mf][nf][r];
          if constexpr (sizeof(OutT) == 2) crow[nf * 16] = f32_bf16(v);
          else                             crow[nf * 16] = v;
        }
      }
    }
#undef GBAR
}

// -------- flash attention: 128 q/block, 32 q/wave (mt=2), 64-key chunks ----
// Swapped QK^T (S^T = mfma(K,Q)): lane owns one query column -> in-lane
// softmax, P packed via cvt_pk and stored as ds_write_b64 (no scalar writes).
// Defer-max (THR=8 exp2-units) skips the O-rescale when max doesn't grow.
// Software-pipelined K/V prefetch into regs; P roundtrip per-wave (no barrier).
// Writes O in place over the Q columns of qkv.
#define KSTR 136  /* 64 x 136 padded K tile  */
#define VSTR 72   /* 128 x 72 padded VT tile */
__global__ __launch_bounds__(256, 2) void attn_kernel(
    unsigned short* qkv, const unsigned short* __restrict__ vT) {
  __shared__ __align__(16) unsigned short Ks[64 * KSTR];
  __shared__ __align__(16) unsigned short Vs[128 * VSTR];
  __shared__ __align__(16) unsigned short Ps[4][32 * VSTR];

  const int t = threadIdx.x, lane = t & 63, w = t >> 6;
  const int quad = lane >> 4, l16 = lane & 15;
  const int q0 = blockIdx.x * 128, h = blockIdx.y, b = blockIdx.z;
  const long row0 = (long)b * SEQ;

  // Q fragments (2 m-tiles): B-operand row = w*32 + mt*16 + l16 (query)
  bf16x8 qf[2][4];
#pragma unroll
  for (int mt = 0; mt < 2; mt++) {
    const unsigned short* Qp =
        qkv + (row0 + q0 + w * 32 + mt * 16 + l16) * (long)QKVO + h * HD + quad * 8;
#pragma unroll
    for (int c = 0; c < 4; c++) qf[mt][c] = *(const bf16x8*)(Qp + c * 32);
  }

  // per-lane stats: lane (quad,l16) owns query mt*16+l16 (replicated over quad)
  float m_l[2], l_l[2];
  f32x4 o[2][8] = {};
  m_l[0] = m_l[1] = -1e30f;
  l_l[0] = l_l[1] = 0.f;
  const float c2 = 0.08838834764831845f * 1.4426950408889634f; // 1/sqrt(128)*log2(e)
  const float thr = 8.0f / c2;  // defer-max threshold in raw-logit domain

  const unsigned short* Kg = qkv + row0 * QKVO + NH * HD + h * HD;
  const unsigned short* Vg = vT + ((long)(b * NH + h)) * HD * SEQ;

  // prefetch chunk 0 into regs
  bf16x8 kr[4], vr[4];
#pragma unroll
  for (int i = 0; i < 4; i++) {
    int s = i * 256 + t;  // K tile: [key = s>>4][dchunk = s&15]
    kr[i] = *(const bf16x8*)(Kg + (long)(s >> 4) * QKVO + (s & 15) * 8);
  }
#pragma unroll
  for (int i = 0; i < 4; i++) {
    int s = i * 256 + t;  // VT tile: [d = s>>3][keychunk = s&7]
    vr[i] = *(const bf16x8*)(Vg + (long)(s >> 3) * SEQ + (s & 7) * 8);
  }

  for (int kc = 0; kc < SEQ; kc += 64) {
    __syncthreads();  // prev chunk's LDS readers done
#pragma unroll
    for (int i = 0; i < 4; i++) {
      int s = i * 256 + t;
      *(bf16x8*)&Ks[(s >> 4) * KSTR + (s & 15) * 8] = kr[i];
    }
#pragma unroll
    for (int i = 0; i < 4; i++) {
      int s = i * 256 + t;
      *(bf16x8*)&Vs[(s >> 3) * VSTR + (s & 7) * 8] = vr[i];
    }
    __syncthreads();  // tiles visible

    // issue next chunk's global loads now; latency hidden under compute
    if (kc + 64 < SEQ) {
#pragma unroll
      for (int i = 0; i < 4; i++) {
        int s = i * 256 + t;
        kr[i] = *(const bf16x8*)(Kg + (long)(kc + 64 + (s >> 4)) * QKVO + (s & 15) * 8);
      }
#pragma unroll
      for (int i = 0; i < 4; i++) {
        int s = i * 256 + t;
        vr[i] = *(const bf16x8*)(Vg + (long)(s >> 3) * SEQ + kc + 64 + (s & 7) * 8);
      }
    }

    // S^T = K Q^T : D row = key (kt*16+quad*4+r), D col = query (l16)
    f32x4 st[2][4];
#pragma unroll
    for (int kt = 0; kt < 4; kt++) {
      f32x4 a0 = {}, a1 = {};
#pragma unroll
      for (int c = 0; c < 4; c++) {
        bf16x8 kf = *(const bf16x8*)&Ks[(kt * 16 + l16) * KSTR + c * 32 + quad * 8];
        a0 = __builtin_amdgcn_mfma_f32_16x16x32_bf16(kf, qf[0][c], a0, 0, 0, 0);
        a1 = __builtin_amdgcn_mfma_f32_16x16x32_bf16(kf, qf[1][c], a1, 0, 0, 0);
      }
      st[0][kt] = a0; st[1][kt] = a1;
    }

    // in-lane online softmax: lane holds 16 keys of its query's row
#pragma unroll
    for (int mt = 0; mt < 2; mt++) {
      float mx0 = fmaxf(fmaxf(st[mt][0][0], st[mt][0][1]),
                        fmaxf(st[mt][0][2], st[mt][0][3]));
      float mx1 = fmaxf(fmaxf(st[mt][1][0], st[mt][1][1]),
                        fmaxf(st[mt][1][2], st[mt][1][3]));
      float mx2 = fmaxf(fmaxf(st[mt][2][0], st[mt][2][1]),
                        fmaxf(st[mt][2][2], st[mt][2][3]));
      float mx3 = fmaxf(fmaxf(st[mt][3][0], st[mt][3][1]),
                        fmaxf(st[mt][3][2], st[mt][3][3]));
      float mx = fmaxf(fmaxf(mx0, mx1), fmaxf(mx2, mx3));
      mx = fmaxf(mx, __shfl_xor(mx, 16, 64));  // combine quads
      mx = fmaxf(mx, __shfl_xor(mx, 32, 64));

      // defer-max: rescale only if some query's max grew past threshold
      if (__any(mx > m_l[mt] + thr)) {
        float mn = fmaxf(m_l[mt], mx);
        float alpha = exp2f(c2 * (m_l[mt] - mn));
        m_l[mt] = mn;
        l_l[mt] *= alpha;
        // redistribute alpha to the O rows this lane holds (queries quad*4+r)
        float a_o[4];
#pragma unroll
        for (int r = 0; r < 4; r++) a_o[r] = __shfl(alpha, (quad << 2) | r, 16);
#pragma unroll
        for (int dt = 0; dt < 8; dt++)
#pragma unroll
          for (int r = 0; r < 4; r++) o[mt][dt][r] *= a_o[r];
      }

      float cm = c2 * m_l[mt];
      float sum = 0.f;
      uint32_t pk0[4], pk1[4];
#pragma unroll
      for (int kt = 0; kt < 4; kt++) {
        float p0 = exp2f(fmaf(st[mt][kt][0], c2, -cm));
        float p1 = exp2f(fmaf(st[mt][kt][1], c2, -cm));
        float p2 = exp2f(fmaf(st[mt][kt][2], c2, -cm));
        float p3 = exp2f(fmaf(st[mt][kt][3], c2, -cm));
        sum += (p0 + p1) + (p2 + p3);
        pk0[kt] = cvt_pk_bf16(p0, p1);
        pk1[kt] = cvt_pk_bf16(p2, p3);
      }
      sum += __shfl_xor(sum, 16, 64);
      sum += __shfl_xor(sum, 32, 64);
      l_l[mt] += sum;

      // P store: lane writes 4 consecutive keys for query l16 -> one b64 each
#pragma unroll
      for (int kt = 0; kt < 4; kt++) {
        uint2 w2; w2.x = pk0[kt]; w2.y = pk1[kt];
        *(uint2*)&Ps[w][(mt * 16 + l16) * VSTR + kt * 16 + quad * 4] = w2;
      }
    }
    asm volatile("s_waitcnt lgkmcnt(0)" ::: "memory");

    // O += P V : V-frag shared across both m-tiles
#pragma unroll
    for (int cc = 0; cc < 2; cc++) {
      bf16x8 pf0 = *(const bf16x8*)&Ps[w][(l16) * VSTR + cc * 32 + quad * 8];
      bf16x8 pf1 = *(const bf16x8*)&Ps[w][(16 + l16) * VSTR + cc * 32 + quad * 8];
#pragma unroll
      for (int dt = 0; dt < 8; dt++) {
        bf16x8 vf = *(const bf16x8*)&Vs[(dt * 16 + l16) * VSTR + cc * 32 + quad * 8];
        o[0][dt] = __builtin_amdgcn_mfma_f32_16x16x32_bf16(pf0, vf, o[0][dt], 0, 0, 0);
        o[1][dt] = __builtin_amdgcn_mfma_f32_16x16x32_bf16(pf1, vf, o[1][dt], 0, 0, 0);
      }
    }
  }

  // epilogue: redistribute 1/l to O rows, write O over the Q columns of qkv
  float inv_o[2][4];
#pragma unroll
  for (int mt = 0; mt < 2; mt++) {
    float linv = 1.f / l_l[mt];
#pragma unroll
    for (int r = 0; r < 4; r++) inv_o[mt][r] = __shfl(linv, (quad << 2) | r, 16);
  }
#pragma unroll
  for (int mt = 0; mt < 2; mt++) {
    long orow = row0 + q0 + w * 32 + mt * 16 + quad * 4;
    unsigned short* Op = qkv + orow * (long)QKVO + h * HD + l16;
#pragma unroll
    for (int r = 0; r < 4; r++) {
#pragma unroll
      for (int dt = 0; dt < 8; dt++)
        Op[(long)r * QKVO + dt * 16] = f32_bf16(o[mt][dt][r] * inv_o[mt][r]);
    }
  }
}

extern "C" void kernel_launch(void* const* d_in, const int* in_sizes, int n_in,
                              void* d_out, int out_size, void* d_ws, size_t ws_size,
                              hipStream_t stream) {
  const float* x     = (const float*)d_in[0];  // [4096][2048] f32
  const float* w_qkv = (const float*)d_in[1];  // [2048][6144] f32
  const float* w_out = (const float*)d_in[2];  // [2048][2048] f32
  float* out = (float*)d_out;                  // [4096][2048] f32

  // Workspace plan (peak 92,274,688 B):
  //   [0,        50331648)  qkv  bf16 [4096][6144] (Q cols later = O)
  //   [50331648, 67108864)  xbf  bf16 [4096][2048]
  //   [67108864, 92274688)  wqkvT bf16 [6144][2048]  (dead after GEMM1)
  //   [67108864, 83886080)    vT bf16 [32][128][2048] (overlays wqkvT)
  //   [83886080, 92274688)    woutT bf16 [2048][2048] (overlays wqkvT tail)
  char* ws = (char*)d_ws;
  unsigned short* qkv   = (unsigned short*)ws;
  unsigned short* xbf   = (unsigned short*)(ws + 50331648);
  unsigned short* wqkvT = (unsigned short*)(ws + 67108864);
  unsigned short* vTbuf = (unsigned short*)(ws + 67108864);
  unsigned short* woutT = (unsigned short*)(ws + 83886080);

  dim3 blk(256);
  // 1) convert x to bf16; transpose+convert w_qkv
  cvt_f32_bf16<<<4096, blk, 0, stream>>>(x, xbf);
  transpose_f32_bf16<<<dim3(QKVO / 64, DIM / 64), blk, 0, stream>>>(w_qkv, wqkvT, DIM, QKVO);
  // 2) QKV projection: qkv = xbf @ w_qkv  (bf16 out) — 8-phase 256² (R7 best)
  gemm256_bt<unsigned short><<<dim3(QKVO / 256, 4096 / 256), dim3(512), 0, stream>>>(
      xbf, DIM, wqkvT, DIM, qkv, QKVO, DIM);
  // 3) V transpose per (b,h) into vT (overlays dead wqkvT)
  transpose_v<<<dim3(SEQ / 64, HD / 64, 2 * NH), blk, 0, stream>>>(qkv, vTbuf);
  // 4) transpose+convert w_out (overlays wqkvT tail; after GEMM1)
  transpose_f32_bf16<<<dim3(DIM / 64, DIM / 64), blk, 0, stream>>>(w_out, woutT, DIM, DIM);
  // 5) flash attention; O written over Q columns of qkv (128 q-rows/block)
  attn_kernel<<<dim3(SEQ / 128, NH, 2), blk, 0, stream>>>(qkv, vTbuf);
  // 6) output projection: 256x128-tile kernel, grid 16x16 = 256 blocks = 1 round
  gemm256x128_bt<float><<<dim3(DIM / 128, 4096 / 256), dim3(512), 0, stream>>>(
      qkv, QKVO, woutT, DIM, out, DIM, DIM);
}